// Round 4
// baseline (120.217 us; speedup 1.0000x reference)
//
#include <hip/hip_runtime.h>

#define LL 96
#define ROWS 128
#define ICHUNK 8
#define LPAD 129  // +1 pad: stride 129 floats -> conflict-free strided access

__global__ __launch_bounds__(ROWS) void gl_loss_kernel(
    const float* __restrict__ yt, const float* __restrict__ yp,
    const float* __restrict__ w, float* __restrict__ out,
    int n, float inv_scale) {
  __shared__ float e_lds[LL][LPAD];

  const int t = threadIdx.x;
  const int b0 = blockIdx.x * ROWS;   // batch-row chunk
  const int i0 = blockIdx.y * ICHUNK; // i chunk
  const int KN = LL - i0;             // rows k in [i0, LL) are needed

  // ---- stage e = yt - yp for rows k in [i0, LL), transposed: e_lds[k][r] ----
  // flat idx -> (r, kk): consecutive idx = consecutive k within a row -> coalesced global reads
  for (int idx = t; idx < ROWS * KN; idx += ROWS) {
    int r = idx / KN;
    int kk = idx - r * KN;
    int k = i0 + kk;
    int b = b0 + r;
    float v = 0.f;
    if (b < n) {
      int g = b * LL + k;
      v = yt[g] - yp[g];
    }
    e_lds[k][r] = v;  // addr = k*129 + r : consecutive r -> consecutive banks
  }
  __syncthreads();

  // each thread owns local row r = t (column t of e_lds)
  float ei[ICHUNK];
#pragma unroll
  for (int u = 0; u < ICHUNK; ++u) ei[u] = e_lds[i0 + u][t];

  float acc = 0.f;

  // ---- head: k in [i0, i0+ICHUNK) — includes the j==0 (k==i) special case ----
  for (int k = i0; k < i0 + ICHUNK; ++k) {
    float ek = e_lds[k][t];
#pragma unroll
    for (int u = 0; u < ICHUNK; ++u) {
      int i = i0 + u;
      if (i < k) {
        int j = k - i;
        float w0 = w[i * LL + j];
        float w1 = w[LL * LL + i * LL + j];
        float d = fabsf(ei[u] - ek);
        acc = fmaf(d, fmaf(d, w1, w0), acc);  // d*w0 + d^2*w1
      } else if (i == k) {
        float w0 = w[i * LL];
        float w1 = w[LL * LL + i * LL];
        float a = fabsf(ei[u]);
        acc = fmaf(a, fmaf(a, w1, w0), acc);  // |e|*w0 + e^2*w1
      }
    }
  }

  // ---- main: k >= i0+ICHUNK — all 8 i's valid, branch-free ----
  for (int k = i0 + ICHUNK; k < LL; ++k) {
    float ek = e_lds[k][t];
#pragma unroll
    for (int u = 0; u < ICHUNK; ++u) {
      int i = i0 + u;
      int j = k - i;
      float w0 = w[i * LL + j];
      float w1 = w[LL * LL + i * LL + j];
      float d = fabsf(ei[u] - ek);
      acc = fmaf(d, fmaf(d, w1, w0), acc);
    }
  }

  // ---- reduce 128 threads -> 1 atomicAdd per block ----
#pragma unroll
  for (int off = 32; off > 0; off >>= 1) acc += __shfl_down(acc, off);

  __shared__ float wsum[ROWS / 64];
  if ((t & 63) == 0) wsum[t >> 6] = acc;
  __syncthreads();
  if (t == 0) {
    float s = 0.f;
#pragma unroll
    for (int wdx = 0; wdx < ROWS / 64; ++wdx) s += wsum[wdx];
    atomicAdd(out, s * inv_scale);
  }
}

extern "C" void kernel_launch(void* const* d_in, const int* in_sizes, int n_in,
                              void* d_out, int out_size, void* d_ws, size_t ws_size,
                              hipStream_t stream) {
  const float* yt = (const float*)d_in[0];
  const float* yp = (const float*)d_in[1];
  const float* w  = (const float*)d_in[2];
  float* out = (float*)d_out;
  int n = in_sizes[0] / LL;

  hipMemsetAsync(out, 0, sizeof(float), stream);

  dim3 grid((n + ROWS - 1) / ROWS, LL / ICHUNK);
  gl_loss_kernel<<<grid, ROWS, 0, stream>>>(yt, yp, w, out, n,
                                            1.0f / (float(LL) * float(n)));
}

// Round 6
// 80.635 us; speedup vs baseline: 1.4909x; 1.4909x over previous
//
#include <hip/hip_runtime.h>

#define LL 96
#define LPADROW 192   // padded LDS row; cols [96,192) are zeros so i+j<=190 is always safe
#define NT 256        // threads per block (4 waves)
#define BROWS 16      // batch rows staged per block
#define JPT 12        // lags j per thread (weights held in 24 VGPRs)
#define NJC 8         // j-chunks per i (8*12 = 96)
#define YBLK 3        // (96 i * 8 jc) / 256 threads
#define NSLOT 64      // partial-sum slots in d_ws

__global__ __launch_bounds__(NT) void gl_loss_main(
    const float* __restrict__ yt, const float* __restrict__ yp,
    const float* __restrict__ w, float* __restrict__ partial, int n) {
  __shared__ float e_lds[BROWS][LPADROW];

  const int t  = threadIdx.x;
  const int c  = blockIdx.y * NT + t;   // cell id in [0, 768)
  const int i  = c >> 3;                // i in [0, 96)
  const int jc = c & 7;                 // j-chunk
  const int j0 = jc * JPT;

  // ---- weights -> registers, once per thread; invalid (i+j>=LL) masked to 0 ----
  float w0r[JPT], w1r[JPT];
#pragma unroll
  for (int jj = 0; jj < JPT; ++jj) {
    int j = j0 + jj;
    bool valid = (i + j) < LL;
    w0r[jj] = valid ? w[i * LL + j] : 0.f;
    w1r[jj] = valid ? w[LL * LL + i * LL + j] : 0.f;
  }
  const float diagmask = (jc == 0) ? 1.f : 0.f;  // j==0 column: |e_i| term

  // ---- stage e = yt - yp (linear coalesced copy), zero the pad columns ----
  const int b0 = blockIdx.x * BROWS;
  for (int f = t; f < BROWS * LPADROW; f += NT) {
    int row = f / LPADROW;
    int col = f - row * LPADROW;
    float v = 0.f;
    int b = b0 + row;
    if (col < LL && b < n) {
      int g = b * LL + col;
      v = yt[g] - yp[g];
    }
    e_lds[row][col] = v;
  }
  __syncthreads();

  // ---- inner loop: pure ds_read + VALU (no SMEM/LDS lgkmcnt mixing) ----
  float acc = 0.f;
  for (int b = 0; b < BROWS; ++b) {
    float ei = e_lds[b][i];
    const float* rowp = &e_lds[b][i + j0];
#pragma unroll
    for (int jj = 0; jj < JPT; ++jj) {
      float d = fabsf(ei - rowp[jj]);              // j==0 cell gives d=0 here
      acc = fmaf(d, fmaf(d, w1r[jj], w0r[jj]), acc);
    }
    // diagonal correction: + |e_i|*w0[i][0] + e_i^2*w1[i][0] for jc==0 threads
    float a = fabsf(ei) * diagmask;
    acc = fmaf(a, fmaf(a, w1r[0], w0r[0]), acc);
  }

  // ---- reduce 256 threads -> one atomic into a spread slot ----
#pragma unroll
  for (int off = 32; off; off >>= 1) acc += __shfl_down(acc, off);
  __shared__ float wsum[NT / 64];
  if ((t & 63) == 0) wsum[t >> 6] = acc;
  __syncthreads();
  if (t == 0) {
    float s = wsum[0] + wsum[1] + wsum[2] + wsum[3];
    atomicAdd(&partial[blockIdx.x & (NSLOT - 1)], s);
  }
}

__global__ __launch_bounds__(64) void gl_loss_fin(
    const float* __restrict__ partial, float* __restrict__ out, float inv_scale) {
  int t = threadIdx.x;
  float v = partial[t];
#pragma unroll
  for (int off = 32; off; off >>= 1) v += __shfl_down(v, off);
  if (t == 0) out[0] = v * inv_scale;
}

extern "C" void kernel_launch(void* const* d_in, const int* in_sizes, int n_in,
                              void* d_out, int out_size, void* d_ws, size_t ws_size,
                              hipStream_t stream) {
  const float* yt = (const float*)d_in[0];
  const float* yp = (const float*)d_in[1];
  const float* w  = (const float*)d_in[2];
  float* out = (float*)d_out;
  int n = in_sizes[0] / LL;

  hipMemsetAsync(d_ws, 0, NSLOT * sizeof(float), stream);

  dim3 grid((n + BROWS - 1) / BROWS, YBLK);
  gl_loss_main<<<grid, NT, 0, stream>>>(yt, yp, w, (float*)d_ws, n);
  gl_loss_fin<<<1, 64, 0, stream>>>((const float*)d_ws, out,
                                    1.0f / (float(LL) * float(n)));
}

// Round 10
// 76.145 us; speedup vs baseline: 1.5788x; 1.0590x over previous
//
#include <hip/hip_runtime.h>

#define LL 96
#define NT 256        // threads per block (4 waves)
#define BROWS 16      // batch rows staged per block
#define KPT 12        // absolute-k cells per thread (48B window, 16B-aligned)
#define YBLK 3        // (96 i * 8 kc) / 256 threads  — rectangle, no division
#define NSLOT 64      // partial-sum slots in d_ws (R6-proven structure)

__global__ __launch_bounds__(NT) void gl_loss_main(
    const float* __restrict__ yt, const float* __restrict__ yp,
    const float* __restrict__ w, float* __restrict__ partial, int n) {
  __shared__ __align__(16) float e_lds[BROWS][LL];  // row = 384B, 16B-aligned

  const int t  = threadIdx.x;
  const int c  = blockIdx.y * NT + t;  // cell id in [0, 768)
  const int i  = c >> 3;               // i in [0, 96)
  const int kc = c & 7;                // k-chunk
  const int k0 = kc * KPT;             // 4-aligned float offset

  // ---- weights -> registers; zero-masked for k <= i (j = k-i >= 1 only) ----
  float w0r[KPT], w1r[KPT];
#pragma unroll
  for (int jj = 0; jj < KPT; ++jj) {
    int k = k0 + jj;
    bool valid = (k > i);
    w0r[jj] = valid ? w[i * LL + (k - i)] : 0.f;
    w1r[jj] = valid ? w[LL * LL + i * LL + (k - i)] : 0.f;
  }
  // diagonal (j==0) term |e_i|: owned by the unique chunk containing k == i
  const bool dg = (i >= k0) && (i < k0 + KPT);
  const float w0d = dg ? w[i * LL] : 0.f;
  const float w1d = dg ? w[LL * LL + i * LL] : 0.f;

  // ---- stage e = yt - yp as float4 (coalesced, 16B-aligned) ----
  const int b0 = blockIdx.x * BROWS;
  float4* ef = (float4*)&e_lds[0][0];  // 384 float4 entries
  for (int f = t; f < BROWS * LL / 4; f += NT) {
    int row = f / (LL / 4);
    int c4  = f - row * (LL / 4);
    int b = b0 + row;
    float4 v = make_float4(0.f, 0.f, 0.f, 0.f);
    if (b < n) {
      const float4 a = *(const float4*)&yt[b * LL + c4 * 4];
      const float4 p = *(const float4*)&yp[b * LL + c4 * 4];
      v = make_float4(a.x - p.x, a.y - p.y, a.z - p.z, a.w - p.w);
    }
    ef[f] = v;
  }
  __syncthreads();

  // ---- inner loop: 1 broadcast ds_read_b32 + 3 ds_read_b128 per row ----
  float acc0 = 0.f, acc1 = 0.f;
#pragma unroll 2
  for (int b = 0; b < BROWS; ++b) {
    float ei = e_lds[b][i];
    float4 vA = *(const float4*)&e_lds[b][k0];
    float4 vB = *(const float4*)&e_lds[b][k0 + 4];
    float4 vC = *(const float4*)&e_lds[b][k0 + 8];
    float ek[KPT] = {vA.x, vA.y, vA.z, vA.w, vB.x, vB.y, vB.z, vB.w,
                     vC.x, vC.y, vC.z, vC.w};
#pragma unroll
    for (int jj = 0; jj < KPT; ++jj) {
      float d = fabsf(ei - ek[jj]);
      if (jj & 1)
        acc1 = fmaf(d, fmaf(d, w1r[jj], w0r[jj]), acc1);
      else
        acc0 = fmaf(d, fmaf(d, w1r[jj], w0r[jj]), acc0);
    }
    float a = fabsf(ei);
    acc1 = fmaf(a, fmaf(a, w1d, w0d), acc1);
  }
  float acc = acc0 + acc1;

  // ---- reduce 256 threads -> one atomic into a spread slot (R6 structure) ----
#pragma unroll
  for (int off = 32; off; off >>= 1) acc += __shfl_down(acc, off);
  __shared__ float wsum[NT / 64];
  if ((t & 63) == 0) wsum[t >> 6] = acc;
  __syncthreads();
  if (t == 0) {
    float s = wsum[0] + wsum[1] + wsum[2] + wsum[3];
    atomicAdd(&partial[blockIdx.x & (NSLOT - 1)], s);
  }
}

__global__ __launch_bounds__(64) void gl_loss_fin(
    const float* __restrict__ partial, float* __restrict__ out, float inv_scale) {
  int t = threadIdx.x;
  float v = partial[t];
#pragma unroll
  for (int off = 32; off; off >>= 1) v += __shfl_down(v, off);
  if (t == 0) out[0] = v * inv_scale;
}

extern "C" void kernel_launch(void* const* d_in, const int* in_sizes, int n_in,
                              void* d_out, int out_size, void* d_ws, size_t ws_size,
                              hipStream_t stream) {
  const float* yt = (const float*)d_in[0];
  const float* yp = (const float*)d_in[1];
  const float* w  = (const float*)d_in[2];
  float* out = (float*)d_out;
  int n = in_sizes[0] / LL;

  hipMemsetAsync(d_ws, 0, NSLOT * sizeof(float), stream);

  dim3 grid((n + BROWS - 1) / BROWS, YBLK);
  gl_loss_main<<<grid, NT, 0, stream>>>(yt, yp, w, (float*)d_ws, n);
  gl_loss_fin<<<1, 64, 0, stream>>>((const float*)d_ws, out,
                                    1.0f / (float(LL) * float(n)));
}

// Round 13
// 75.981 us; speedup vs baseline: 1.5822x; 1.0022x over previous
//
#include <hip/hip_runtime.h>

#define LL 96
#define NT 256        // threads per block (4 waves)
#define BROWS 32      // batch rows staged per block
#define KPT 12        // absolute-k cells per thread (48B window, 16B-aligned)
#define YBLK 3        // (96 i * 8 kc) / 256 threads — rectangle mapping, no division

__global__ __launch_bounds__(NT) void gl_loss_main(
    const float* __restrict__ yt, const float* __restrict__ yp,
    const float* __restrict__ w, float* __restrict__ out,
    int n, float inv_scale) {
  __shared__ __align__(16) float e_lds[BROWS][LL];  // row = 384B, 16B-aligned

  const int t  = threadIdx.x;
  const int c  = blockIdx.y * NT + t;  // cell id in [0, 768)
  const int i  = c >> 3;               // i in [0, 96)
  const int kc = c & 7;                // k-chunk
  const int k0 = kc * KPT;             // 4-aligned float offset

  // ---- weights -> registers; zero-masked for k <= i (j = k-i >= 1 only) ----
  float w0r[KPT], w1r[KPT];
#pragma unroll
  for (int jj = 0; jj < KPT; ++jj) {
    int k = k0 + jj;
    bool valid = (k > i);
    w0r[jj] = valid ? w[i * LL + (k - i)] : 0.f;
    w1r[jj] = valid ? w[LL * LL + i * LL + (k - i)] : 0.f;
  }
  // diagonal (j==0) term |e_i|: owned by the unique chunk containing k == i
  const bool dg = (i >= k0) && (i < k0 + KPT);
  const float w0d = dg ? w[i * LL] : 0.f;
  const float w1d = dg ? w[LL * LL + i * LL] : 0.f;

  // ---- stage e = yt - yp as float4 (coalesced, 16B-aligned) ----
  const int b0 = blockIdx.x * BROWS;
  float4* ef = (float4*)&e_lds[0][0];  // 768 float4 entries
  for (int f = t; f < BROWS * LL / 4; f += NT) {
    int row = f / (LL / 4);
    int c4  = f - row * (LL / 4);
    int b = b0 + row;
    float4 v = make_float4(0.f, 0.f, 0.f, 0.f);
    if (b < n) {
      const float4 a = *(const float4*)&yt[b * LL + c4 * 4];
      const float4 p = *(const float4*)&yp[b * LL + c4 * 4];
      v = make_float4(a.x - p.x, a.y - p.y, a.z - p.z, a.w - p.w);
    }
    ef[f] = v;
  }
  __syncthreads();

  // ---- inner loop: 1 broadcast ds_read_b32 + 3 ds_read_b128 per row ----
  float acc0 = 0.f, acc1 = 0.f;
#pragma unroll 2
  for (int b = 0; b < BROWS; ++b) {
    float ei = e_lds[b][i];
    float4 vA = *(const float4*)&e_lds[b][k0];
    float4 vB = *(const float4*)&e_lds[b][k0 + 4];
    float4 vC = *(const float4*)&e_lds[b][k0 + 8];
    float ek[KPT] = {vA.x, vA.y, vA.z, vA.w, vB.x, vB.y, vB.z, vB.w,
                     vC.x, vC.y, vC.z, vC.w};
#pragma unroll
    for (int jj = 0; jj < KPT; ++jj) {
      float d = fabsf(ei - ek[jj]);
      if (jj & 1)
        acc1 = fmaf(d, fmaf(d, w1r[jj], w0r[jj]), acc1);
      else
        acc0 = fmaf(d, fmaf(d, w1r[jj], w0r[jj]), acc0);
    }
    float a = fabsf(ei);
    acc1 = fmaf(a, fmaf(a, w1d, w0d), acc1);
  }
  float acc = acc0 + acc1;

  // ---- reduce 256 threads -> ONE atomic direct to out (R4-proven structure) ----
#pragma unroll
  for (int off = 32; off; off >>= 1) acc += __shfl_down(acc, off);
  __shared__ float wsum[NT / 64];
  if ((t & 63) == 0) wsum[t >> 6] = acc;
  __syncthreads();
  if (t == 0) {
    float s = wsum[0] + wsum[1] + wsum[2] + wsum[3];
    atomicAdd(out, s * inv_scale);
  }
}

extern "C" void kernel_launch(void* const* d_in, const int* in_sizes, int n_in,
                              void* d_out, int out_size, void* d_ws, size_t ws_size,
                              hipStream_t stream) {
  const float* yt = (const float*)d_in[0];
  const float* yp = (const float*)d_in[1];
  const float* w  = (const float*)d_in[2];
  float* out = (float*)d_out;
  int n = in_sizes[0] / LL;

  dim3 grid((n + BROWS - 1) / BROWS, YBLK);
  gl_loss_main<<<grid, NT, 0, stream>>>(yt, yp, w, out, n,
                                        1.0f / (float(LL) * float(n)));
}

// Round 15
// 75.618 us; speedup vs baseline: 1.5898x; 1.0048x over previous
//
#include <hip/hip_runtime.h>

#define LL 96
#define NT 256        // threads per block (4 waves)
#define BROWS 32      // batch rows staged per block
#define KPT 12        // absolute-k cells per thread (48B window, 16B-aligned)
#define IPB 32        // i-values per y-slice (256 cells / 8 kc)
#define YBLK 3        // 96 i / 32 i-per-block

__global__ __launch_bounds__(NT) void gl_loss_main(
    const float* __restrict__ yt, const float* __restrict__ yp,
    const float* __restrict__ w, float* __restrict__ out,
    int n, float inv_scale) {
  __shared__ __align__(16) float w_lds[2][IPB][LL];  // 24 KB: this slice's weight rows
  __shared__ __align__(16) float e_lds[BROWS][LL];   // 12 KB

  const int t   = threadIdx.x;
  const int by  = blockIdx.y;
  const int i0g = by * IPB;        // first i of this y-slice
  const int il  = t >> 3;          // local i within slice
  const int i   = i0g + il;        // global i
  const int kc  = t & 7;           // k-chunk
  const int k0  = kc * KPT;        // 4-aligned float offset

  // ---- stage weight rows for this slice: coalesced float4 from L2-hot w ----
  {
    float4* wl = (float4*)&w_lds[0][0][0];           // 1536 float4
    for (int f = t; f < 2 * IPB * LL / 4; f += NT) {
      int plane = f / (IPB * LL / 4);                // 0 or 1
      int rem   = f - plane * (IPB * LL / 4);
      int row   = rem / (LL / 4);
      int c4    = rem - row * (LL / 4);
      wl[f] = *(const float4*)&w[plane * LL * LL + (i0g + row) * LL + c4 * 4];
    }
  }

  // ---- stage e = yt - yp as float4 (coalesced, 16B-aligned) ----
  const int b0 = blockIdx.x * BROWS;
  {
    float4* ef = (float4*)&e_lds[0][0];              // 768 float4
    for (int f = t; f < BROWS * LL / 4; f += NT) {
      int row = f / (LL / 4);
      int c4  = f - row * (LL / 4);
      int b = b0 + row;
      float4 v = make_float4(0.f, 0.f, 0.f, 0.f);
      if (b < n) {
        const float4 a = *(const float4*)&yt[b * LL + c4 * 4];
        const float4 p = *(const float4*)&yp[b * LL + c4 * 4];
        v = make_float4(a.x - p.x, a.y - p.y, a.z - p.z, a.w - p.w);
      }
      ef[f] = v;
    }
  }
  __syncthreads();

  // ---- hoist this thread's 26 weights from LDS to registers ----
  float w0r[KPT], w1r[KPT];
#pragma unroll
  for (int jj = 0; jj < KPT; ++jj) {
    int k = k0 + jj;
    bool valid = (k > i);
    int j = valid ? (k - i) : 1;                      // clamped in-bounds read
    w0r[jj] = valid ? w_lds[0][il][j] : 0.f;
    w1r[jj] = valid ? w_lds[1][il][j] : 0.f;
  }
  const bool dg = (i >= k0) && (i < k0 + KPT);        // diagonal (j==0) owner
  const float w0d = dg ? w_lds[0][il][0] : 0.f;
  const float w1d = dg ? w_lds[1][il][0] : 0.f;

  // ---- inner loop: 1 broadcast ds_read_b32 + 3 ds_read_b128 per row ----
  float acc0 = 0.f, acc1 = 0.f;
#pragma unroll 2
  for (int b = 0; b < BROWS; ++b) {
    float ei = e_lds[b][i];
    float4 vA = *(const float4*)&e_lds[b][k0];
    float4 vB = *(const float4*)&e_lds[b][k0 + 4];
    float4 vC = *(const float4*)&e_lds[b][k0 + 8];
    float ek[KPT] = {vA.x, vA.y, vA.z, vA.w, vB.x, vB.y, vB.z, vB.w,
                     vC.x, vC.y, vC.z, vC.w};
#pragma unroll
    for (int jj = 0; jj < KPT; ++jj) {
      float d = fabsf(ei - ek[jj]);
      if (jj & 1)
        acc1 = fmaf(d, fmaf(d, w1r[jj], w0r[jj]), acc1);
      else
        acc0 = fmaf(d, fmaf(d, w1r[jj], w0r[jj]), acc0);
    }
    float a = fabsf(ei);
    acc1 = fmaf(a, fmaf(a, w1d, w0d), acc1);
  }
  float acc = acc0 + acc1;

  // ---- reduce 256 threads -> ONE atomic direct to out (R13-proven) ----
#pragma unroll
  for (int off = 32; off; off >>= 1) acc += __shfl_down(acc, off);
  __shared__ float wsum[NT / 64];
  if ((t & 63) == 0) wsum[t >> 6] = acc;
  __syncthreads();
  if (t == 0) {
    float s = wsum[0] + wsum[1] + wsum[2] + wsum[3];
    atomicAdd(out, s * inv_scale);
  }
}

extern "C" void kernel_launch(void* const* d_in, const int* in_sizes, int n_in,
                              void* d_out, int out_size, void* d_ws, size_t ws_size,
                              hipStream_t stream) {
  const float* yt = (const float*)d_in[0];
  const float* yp = (const float*)d_in[1];
  const float* w  = (const float*)d_in[2];
  float* out = (float*)d_out;
  int n = in_sizes[0] / LL;

  dim3 grid((n + BROWS - 1) / BROWS, YBLK);
  gl_loss_main<<<grid, NT, 0, stream>>>(yt, yp, w, out, n,
                                        1.0f / (float(LL) * float(n)));
}

// Round 17
// 73.931 us; speedup vs baseline: 1.6261x; 1.0228x over previous
//
#include <hip/hip_runtime.h>

#define LL 96
#define NT 256        // threads per block (4 waves)
#define BROWS 16      // batch rows staged per block
#define KPT 12        // k-cells per window (48B, 16B-aligned)
#define NI 3          // i-values per thread (stride 32): window reused 3x

__global__ __launch_bounds__(NT) void gl_loss_main(
    const float* __restrict__ yt, const float* __restrict__ yp,
    const float* __restrict__ w, float* __restrict__ out,
    int n, float inv_scale) {
  __shared__ __align__(16) float e_lds[BROWS][LL];  // 6 KB

  const int t  = threadIdx.x;
  const int ig = t >> 3;           // 0..31
  const int kc = t & 7;            // k-chunk
  const int k0 = kc * KPT;         // 4-aligned float offset

  // ---- weights -> registers for all 3 owned i-values (global, L2-hot) ----
  float w0r[NI][KPT], w1r[NI][KPT], w0d[NI], w1d[NI];
#pragma unroll
  for (int m = 0; m < NI; ++m) {
    int i = ig + 32 * m;
#pragma unroll
    for (int jj = 0; jj < KPT; ++jj) {
      int k = k0 + jj;
      bool valid = (k > i);                      // j = k-i >= 1 only
      w0r[m][jj] = valid ? w[i * LL + (k - i)] : 0.f;
      w1r[m][jj] = valid ? w[LL * LL + i * LL + (k - i)] : 0.f;
    }
    bool dg = (i >= k0) && (i < k0 + KPT);       // diagonal (j==0) owner
    w0d[m] = dg ? w[i * LL] : 0.f;
    w1d[m] = dg ? w[LL * LL + i * LL] : 0.f;
  }

  // ---- stage e = yt - yp as float4 (coalesced, 16B-aligned) ----
  const int b0 = blockIdx.x * BROWS;
  {
    float4* ef = (float4*)&e_lds[0][0];          // 384 float4
    for (int f = t; f < BROWS * LL / 4; f += NT) {
      int row = f / (LL / 4);
      int c4  = f - row * (LL / 4);
      int b = b0 + row;
      float4 v = make_float4(0.f, 0.f, 0.f, 0.f);
      if (b < n) {
        const float4 a = *(const float4*)&yt[b * LL + c4 * 4];
        const float4 p = *(const float4*)&yp[b * LL + c4 * 4];
        v = make_float4(a.x - p.x, a.y - p.y, a.z - p.z, a.w - p.w);
      }
      ef[f] = v;
    }
  }
  __syncthreads();

  // ---- inner loop: one k-window (3 b128) serves 3 i-values (3 b32) ----
  float acc0 = 0.f, acc1 = 0.f;
#pragma unroll 2
  for (int b = 0; b < BROWS; ++b) {
    float4 vA = *(const float4*)&e_lds[b][k0];
    float4 vB = *(const float4*)&e_lds[b][k0 + 4];
    float4 vC = *(const float4*)&e_lds[b][k0 + 8];
    float ek[KPT] = {vA.x, vA.y, vA.z, vA.w, vB.x, vB.y, vB.z, vB.w,
                     vC.x, vC.y, vC.z, vC.w};
#pragma unroll
    for (int m = 0; m < NI; ++m) {
      float ei = e_lds[b][ig + 32 * m];
#pragma unroll
      for (int jj = 0; jj < KPT; ++jj) {
        float d = fabsf(ei - ek[jj]);
        if (jj & 1)
          acc1 = fmaf(d, fmaf(d, w1r[m][jj], w0r[m][jj]), acc1);
        else
          acc0 = fmaf(d, fmaf(d, w1r[m][jj], w0r[m][jj]), acc0);
      }
      float a = fabsf(ei);                       // diagonal |e_i| term
      acc1 = fmaf(a, fmaf(a, w1d[m], w0d[m]), acc1);
    }
  }
  float acc = acc0 + acc1;

  // ---- reduce 256 threads -> ONE atomic direct to out (R13/R15-proven) ----
#pragma unroll
  for (int off = 32; off; off >>= 1) acc += __shfl_down(acc, off);
  __shared__ float wsum[NT / 64];
  if ((t & 63) == 0) wsum[t >> 6] = acc;
  __syncthreads();
  if (t == 0) {
    float s = wsum[0] + wsum[1] + wsum[2] + wsum[3];
    atomicAdd(out, s * inv_scale);
  }
}

extern "C" void kernel_launch(void* const* d_in, const int* in_sizes, int n_in,
                              void* d_out, int out_size, void* d_ws, size_t ws_size,
                              hipStream_t stream) {
  const float* yt = (const float*)d_in[0];
  const float* yp = (const float*)d_in[1];
  const float* w  = (const float*)d_in[2];
  float* out = (float*)d_out;
  int n = in_sizes[0] / LL;

  dim3 grid((n + BROWS - 1) / BROWS, 1);
  gl_loss_main<<<grid, NT, 0, stream>>>(yt, yp, w, out, n,
                                        1.0f / (float(LL) * float(n)));
}